// Round 4
// baseline (547.293 us; speedup 1.0000x reference)
//
#include <hip/hip_runtime.h>

#define N_NODES 100000
#define N_EDGES 1600000
#define NREP 16

typedef __attribute__((ext_vector_type(8))) short short8;
typedef __attribute__((ext_vector_type(4))) float f32x4;

__device__ inline float bf2f(unsigned short h) {
    union { unsigned int u; float f; } v; v.u = ((unsigned int)h) << 16; return v.f;
}
__device__ inline unsigned short f2bf(float f) {
    union { unsigned int u; float f; } v; v.f = f;
    unsigned int u = v.u;
    return (unsigned short)((u + 0x7fffu + ((u >> 16) & 1u)) >> 16);
}

// ---------------------------------------------------------------- degree hist (privatized x16)
__global__ void degree_repl_kernel(const int* __restrict__ src, const int* __restrict__ dst,
                                   int* __restrict__ hist_src, int* __restrict__ hist_dst) {
    int e = blockIdx.x * blockDim.x + threadIdx.x;
    int r = blockIdx.x & (NREP - 1);
    if (e < N_EDGES) {
        atomicAdd(&hist_src[r * N_NODES + src[e]], 1);
        atomicAdd(&hist_dst[r * N_NODES + dst[e]], 1);
    }
}

// ---------------------------------------------------------------- replica reduce + norms
__global__ void reduce_norm_kernel(const int* __restrict__ hist_src, const int* __restrict__ hist_dst,
                                   int* __restrict__ deg_in, float* __restrict__ out_norm,
                                   float* __restrict__ in_norm) {
    int n = blockIdx.x * blockDim.x + threadIdx.x;
    if (n >= N_NODES) return;
    int so = 0, si = 0;
    #pragma unroll
    for (int r = 0; r < NREP; r++) {
        so += hist_src[r * N_NODES + n];
        si += hist_dst[r * N_NODES + n];
    }
    deg_in[n] = si;
    out_norm[n] = rsqrtf((float)(so < 1 ? 1 : so));
    in_norm[n]  = rsqrtf((float)(si < 1 ? 1 : si));
}

// ---------------------------------------------------------------- 1-block scan
__global__ void scan_kernel(const int* __restrict__ deg, int* __restrict__ row_ptr) {
    __shared__ int sums[1024];
    int t = threadIdx.x;
    int s = 0;
    if (t < 1000) {
        const int4* d4 = (const int4*)(deg + t * 100);
        #pragma unroll
        for (int i = 0; i < 25; i++) { int4 v = d4[i]; s += v.x + v.y + v.z + v.w; }
    }
    sums[t] = s;
    __syncthreads();
    for (int st = 1; st < 1024; st <<= 1) {
        int v = (t >= st) ? sums[t - st] : 0;
        __syncthreads();
        sums[t] += v;
        __syncthreads();
    }
    if (t < 1000) {
        int base = (t == 0) ? 0 : sums[t - 1];
        for (int i = 0; i < 100; i++) { row_ptr[t * 100 + i] = base; base += deg[t * 100 + i]; }
    }
    if (t == 1023) row_ptr[N_NODES] = sums[1023];
}

// ---------------------------------------------------------------- per-replica absolute bases
// converts hist_dst[r][n] (counts) in place into absolute CSR write bases
__global__ void base_kernel(const int* __restrict__ row_ptr, int* __restrict__ base) {
    int n = blockIdx.x * blockDim.x + threadIdx.x;
    if (n >= N_NODES) return;
    int run = row_ptr[n];
    #pragma unroll
    for (int r = 0; r < NREP; r++) {
        int c = base[r * N_NODES + n];
        base[r * N_NODES + n] = run;
        run += c;
    }
}

// ---------------------------------------------------------------- CSR fill (privatized)
__global__ void fill_repl_kernel(const int* __restrict__ src, const int* __restrict__ dst,
                                 int* __restrict__ base, int* __restrict__ csr_src) {
    int e = blockIdx.x * blockDim.x + threadIdx.x;
    int r = blockIdx.x & (NREP - 1);
    if (e < N_EDGES) {
        int pos = atomicAdd(&base[r * N_NODES + dst[e]], 1);
        csr_src[pos] = src[e];
    }
}

// ---------------------------------------------------------------- weight prep
__global__ void tconv_kernel(const float* __restrict__ in, unsigned short* __restrict__ out,
                             int NN, int KK) {   // in [KK][NN] -> out [NN][KK] bf16
    int idx = blockIdx.x * blockDim.x + threadIdx.x;
    if (idx >= NN * KK) return;
    int n = idx / KK, k = idx % KK;
    out[idx] = f2bf(in[(size_t)k * NN + n]);
}
__global__ void conv_kernel(const float* __restrict__ in, unsigned short* __restrict__ out,
                            int total) {
    int idx = blockIdx.x * blockDim.x + threadIdx.x;
    if (idx < total) out[idx] = f2bf(in[idx]);
}

// ---------------------------------------------------------------- prescale x*out_norm -> bf16
__global__ void prescale_kernel(const float4* __restrict__ in, const float* __restrict__ out_norm,
                                ushort4* __restrict__ out) {
    int idx = blockIdx.x * blockDim.x + threadIdx.x;
    if (idx >= N_NODES * 32) return;
    float sc = out_norm[idx >> 5];
    float4 v = in[idx];
    ushort4 o;
    o.x = f2bf(v.x * sc); o.y = f2bf(v.y * sc); o.z = f2bf(v.z * sc); o.w = f2bf(v.w * sc);
    out[idx] = o;
}

// ---------------------------------------------------------------- aggregation
// one wave per dst node; half-wave (32 lanes x ushort4 = 256B) covers one bf16 row;
// 4 gathers per half unrolled -> 8 independent row gathers in flight per wave.
// EPI 0: out_bf = bf16(sum * in_norm)          (agg1)
// EPI 1: v = relu(sum*in_norm + b2); half0 -> f32 out, half1 -> bf16 out   (agg2)
template<int EPI>
__global__ __launch_bounds__(256) void aggregate_bf(
    const ushort4* __restrict__ x, const int* __restrict__ row_ptr,
    const int* __restrict__ csr_src, const float* __restrict__ in_norm,
    const float* __restrict__ b2, float4* __restrict__ outF,
    ushort4* __restrict__ outB) {
    int wave = threadIdx.x >> 6, lane = threadIdx.x & 63;
    int n = blockIdx.x * 4 + wave;
    if (n >= N_NODES) return;
    int half = lane >> 5, cl = lane & 31;
    int s0 = row_ptr[n], s1 = row_ptr[n + 1];
    float ax = 0, ay = 0, az = 0, aw = 0;
    float bx = 0, by = 0, bz = 0, bw = 0;
    int i = s0 + half;
    for (; i + 6 < s1; i += 8) {
        int sA = csr_src[i],     sB = csr_src[i + 2];
        int sC = csr_src[i + 4], sD = csr_src[i + 6];
        ushort4 va = x[(size_t)sA * 32 + cl];
        ushort4 vb = x[(size_t)sB * 32 + cl];
        ushort4 vc = x[(size_t)sC * 32 + cl];
        ushort4 vd = x[(size_t)sD * 32 + cl];
        ax += bf2f(va.x); ay += bf2f(va.y); az += bf2f(va.z); aw += bf2f(va.w);
        bx += bf2f(vb.x); by += bf2f(vb.y); bz += bf2f(vb.z); bw += bf2f(vb.w);
        ax += bf2f(vc.x); ay += bf2f(vc.y); az += bf2f(vc.z); aw += bf2f(vc.w);
        bx += bf2f(vd.x); by += bf2f(vd.y); bz += bf2f(vd.z); bw += bf2f(vd.w);
    }
    for (; i < s1; i += 2) {
        ushort4 va = x[(size_t)csr_src[i] * 32 + cl];
        ax += bf2f(va.x); ay += bf2f(va.y); az += bf2f(va.z); aw += bf2f(va.w);
    }
    ax += bx; ay += by; az += bz; aw += bw;
    ax += __shfl_xor(ax, 32);
    ay += __shfl_xor(ay, 32);
    az += __shfl_xor(az, 32);
    aw += __shfl_xor(aw, 32);
    float inn = in_norm[n];
    if (EPI == 0) {
        if (half == 0) {
            ushort4 o;
            o.x = f2bf(ax * inn); o.y = f2bf(ay * inn);
            o.z = f2bf(az * inn); o.w = f2bf(aw * inn);
            outB[(size_t)n * 32 + cl] = o;
        }
    } else {
        float4 bv = ((const float4*)b2)[cl];
        float vx = fmaxf(fmaf(ax, inn, bv.x), 0.f);
        float vy = fmaxf(fmaf(ay, inn, bv.y), 0.f);
        float vz = fmaxf(fmaf(az, inn, bv.z), 0.f);
        float vw = fmaxf(fmaf(aw, inn, bv.w), 0.f);
        if (half == 0) {
            outF[(size_t)n * 32 + cl] = make_float4(vx, vy, vz, vw);
        } else {
            ushort4 o;
            o.x = f2bf(vx); o.y = f2bf(vy); o.z = f2bf(vz); o.w = f2bf(vw);
            outB[(size_t)n * 32 + cl] = o;
        }
    }
}

// ---------------------------------------------------------------- bf16 MFMA GEMM
// C[M x 128-tile] = A[M][K](bf16) @ Bt[N][K](bf16)^T; full-K in one block.
// EPI: 0 = f32 store; 1 = bf16(relu(v+aux[col])); 2 = bf16(v*aux[row])
template<int K, int EPI>
__global__ __launch_bounds__(256) void gemm_mfma(
    const unsigned short* __restrict__ A, const unsigned short* __restrict__ Bt,
    const float* __restrict__ aux, void* __restrict__ Cv, int ldc, int M) {
    constexpr int CH = K / 8;
    __shared__ short blds[128 * K];
    int tid = threadIdx.x;
    int bn = blockIdx.x * 128;
    int bm = blockIdx.y * 128;
    {
        const short8* g = (const short8*)Bt;
        short8* l = (short8*)blds;
        for (int id = tid; id < 128 * CH; id += 256) {
            int col = id / CH, kc = id % CH;
            l[col * CH + (kc ^ (col & (CH - 1)))] = g[(size_t)(bn + col) * CH + kc];
        }
    }
    __syncthreads();
    int wm = tid >> 6, lane = tid & 63;
    int lr = lane & 15, kq = lane >> 4;
    int r0 = bm + wm * 32 + lr;
    int r1 = r0 + 16;
    const short8* A8 = (const short8*)A;
    size_t a0row = (size_t)(r0 < M ? r0 : 0) * CH;
    size_t a1row = (size_t)(r1 < M ? r1 : 0) * CH;
    const short8* l8 = (const short8*)blds;

    f32x4 acc[2][8];
    #pragma unroll
    for (int m = 0; m < 2; m++)
        #pragma unroll
        for (int j = 0; j < 8; j++) acc[m][j] = (f32x4)0.f;

    short8 a0 = A8[a0row + kq];
    short8 a1 = A8[a1row + kq];
    for (int kc2 = 0; kc2 < K / 32; kc2++) {
        int kc = kc2 * 4 + kq;
        short8 n0, n1;
        if (kc2 + 1 < K / 32) {
            n0 = A8[a0row + kc + 4];
            n1 = A8[a1row + kc + 4];
        }
        #pragma unroll
        for (int nj = 0; nj < 8; nj++) {
            int col = nj * 16 + lr;
            short8 b = l8[col * CH + (kc ^ (col & (CH - 1)))];
            acc[0][nj] = __builtin_amdgcn_mfma_f32_16x16x32_bf16(a0, b, acc[0][nj], 0, 0, 0);
            acc[1][nj] = __builtin_amdgcn_mfma_f32_16x16x32_bf16(a1, b, acc[1][nj], 0, 0, 0);
        }
        a0 = n0; a1 = n1;
    }

    #pragma unroll
    for (int mi = 0; mi < 2; mi++) {
        #pragma unroll
        for (int i = 0; i < 4; i++) {
            int gr = bm + wm * 32 + mi * 16 + kq * 4 + i;
            if (gr >= M) continue;
            float sc = (EPI == 2) ? aux[gr] : 0.f;
            #pragma unroll
            for (int nj = 0; nj < 8; nj++) {
                int col = bn + nj * 16 + lr;
                float v = acc[mi][nj][i];
                if (EPI == 0)
                    ((float*)Cv)[(size_t)gr * ldc + col] = v;
                else if (EPI == 1)
                    ((unsigned short*)Cv)[(size_t)gr * ldc + col] = f2bf(fmaxf(v + aux[col], 0.f));
                else
                    ((unsigned short*)Cv)[(size_t)gr * ldc + col] = f2bf(v * sc);
            }
        }
    }
}

// ================================================================ launch
extern "C" void kernel_launch(void* const* d_in, const int* in_sizes, int n_in,
                              void* d_out, int out_size, void* d_ws, size_t ws_size,
                              hipStream_t stream) {
    const float* in_feat = (const float*)d_in[0];
    const int*   src     = (const int*)d_in[1];
    const int*   dst     = (const int*)d_in[2];
    const float* W1      = (const float*)d_in[3];   // [128][256]
    const float* b1      = (const float*)d_in[4];
    const float* W2      = (const float*)d_in[5];   // [256][128]
    const float* b2      = (const float*)d_in[6];
    const float* fc1_w   = (const float*)d_in[7];
    const float* fc2_w   = (const float*)d_in[8];

    float* out = (float*)d_out;
    float* h_out = out;                              // [100000][128] f32 (final)
    float* feat1 = out + (size_t)12800000;
    float* feat2 = out + (size_t)25600000;
    // scratch aliases in d_out (lifetimes verified against writers):
    unsigned short* xs_bf   = (unsigned short*)out;              // dies before agg2 writes h
    unsigned short* agg1_bf = (unsigned short*)(out + 6400000);  // dies before agg2 writes h
    unsigned short* h1_bf   = (unsigned short*)(out + 12800000); // dies before feat1 written
    unsigned short* x2_bf   = (unsigned short*)(out + 25600000); // dies before feat2 written

    int* hist_src = (int*)d_ws;                      // [16][100000]
    int* base     = hist_src + NREP * N_NODES;       // [16][100000] (dst hist -> bases -> counters)
    int* deg_in   = base + NREP * N_NODES;           // 100000
    int* row_ptr  = deg_in + 100000;                 // 100004
    int* csr_src  = row_ptr + 100004;                // 1600000
    float* out_norm = (float*)(csr_src + 1600000);
    float* in_norm  = out_norm + 100000;
    unsigned short* Wt1  = (unsigned short*)(in_norm + 100000);  // [256][128]
    unsigned short* Wt2  = Wt1 + 32768;                          // [128][256]
    unsigned short* fc1b = Wt2 + 32768;
    unsigned short* fc2b = fc1b + 16384;
    unsigned short* h_bf = fc2b + 16384;                         // [100000][128]

    // zero the two replica histograms (12.8 MB contiguous)
    hipMemsetAsync(hist_src, 0, (size_t)2 * NREP * N_NODES * sizeof(int), stream);

    degree_repl_kernel<<<(N_EDGES + 255) / 256, 256, 0, stream>>>(src, dst, hist_src, base);
    reduce_norm_kernel<<<(N_NODES + 255) / 256, 256, 0, stream>>>(hist_src, base, deg_in,
                                                                  out_norm, in_norm);
    scan_kernel<<<1, 1024, 0, stream>>>(deg_in, row_ptr);
    base_kernel<<<(N_NODES + 255) / 256, 256, 0, stream>>>(row_ptr, base);
    fill_repl_kernel<<<(N_EDGES + 255) / 256, 256, 0, stream>>>(src, dst, base, csr_src);

    tconv_kernel<<<128, 256, 0, stream>>>(W1, Wt1, 256, 128);
    tconv_kernel<<<128, 256, 0, stream>>>(W2, Wt2, 128, 256);
    conv_kernel<<<64, 256, 0, stream>>>(fc1_w, fc1b, 16384);
    conv_kernel<<<64, 256, 0, stream>>>(fc2_w, fc2b, 16384);

    prescale_kernel<<<12500, 256, 0, stream>>>((const float4*)in_feat, out_norm, (ushort4*)xs_bf);

    aggregate_bf<0><<<25000, 256, 0, stream>>>((const ushort4*)xs_bf, row_ptr, csr_src,
                                               in_norm, nullptr, nullptr, (ushort4*)agg1_bf);

    gemm_mfma<128, 1><<<dim3(2, 782), 256, 0, stream>>>(agg1_bf, Wt1, b1, h1_bf, 256, N_NODES);
    gemm_mfma<256, 2><<<dim3(1, 782), 256, 0, stream>>>(h1_bf, Wt2, out_norm, x2_bf, 128, N_NODES);

    aggregate_bf<1><<<25000, 256, 0, stream>>>((const ushort4*)x2_bf, row_ptr, csr_src,
                                               in_norm, b2, (float4*)h_out, (ushort4*)h_bf);

    gemm_mfma<128, 0><<<dim3(1, 782), 256, 0, stream>>>(h_bf, fc1b, nullptr, feat1, 128, N_NODES);
    gemm_mfma<128, 0><<<dim3(1, 782), 256, 0, stream>>>(h_bf, fc2b, nullptr, feat2, 128, N_NODES);
}

// Round 5
// 405.188 us; speedup vs baseline: 1.3507x; 1.3507x over previous
//
#include <hip/hip_runtime.h>

#define N_NODES 100000
#define N_EDGES 1600000
#define P_PARTS 8
#define S_SLICES 32
#define NP 12500     // nodes per partition
#define ES 50000     // edges per slice

typedef __attribute__((ext_vector_type(8))) short short8;
typedef __attribute__((ext_vector_type(4))) float f32x4;

__device__ inline float bf2f(unsigned short h) {
    union { unsigned int u; float f; } v; v.u = ((unsigned int)h) << 16; return v.f;
}
__device__ inline unsigned short f2bf(float f) {
    union { unsigned int u; float f; } v; v.f = f;
    unsigned int u = v.u;
    return (unsigned short)((u + 0x7fffu + ((u >> 16) & 1u)) >> 16);
}

// ---------------------------------------------------------------- partitioned LDS histograms
// block (p,s): p = blockIdx&7 (node range), s = blockIdx>>3 (edge slice).
// LDS hist of src and dst for range p over slice s; no global atomics.
__global__ __launch_bounds__(256) void hist_part_kernel(
    const int* __restrict__ src, const int* __restrict__ dst,
    int* __restrict__ part_src, int* __restrict__ part_dst) {
    __shared__ int hs[NP];
    __shared__ int hd[NP];
    int tid = threadIdx.x;
    int p = blockIdx.x & (P_PARTS - 1), s = blockIdx.x >> 3;
    for (int j = tid; j < NP; j += 256) { hs[j] = 0; hd[j] = 0; }
    __syncthreads();
    int lo = p * NP;
    const int4* s4 = (const int4*)(src + s * ES);
    const int4* d4 = (const int4*)(dst + s * ES);
    for (int i = tid; i < ES / 4; i += 256) {
        int4 sv = s4[i];
        int4 dv = d4[i];
        int a;
        a = sv.x - lo; if ((unsigned)a < NP) atomicAdd(&hs[a], 1);
        a = sv.y - lo; if ((unsigned)a < NP) atomicAdd(&hs[a], 1);
        a = sv.z - lo; if ((unsigned)a < NP) atomicAdd(&hs[a], 1);
        a = sv.w - lo; if ((unsigned)a < NP) atomicAdd(&hs[a], 1);
        a = dv.x - lo; if ((unsigned)a < NP) atomicAdd(&hd[a], 1);
        a = dv.y - lo; if ((unsigned)a < NP) atomicAdd(&hd[a], 1);
        a = dv.z - lo; if ((unsigned)a < NP) atomicAdd(&hd[a], 1);
        a = dv.w - lo; if ((unsigned)a < NP) atomicAdd(&hd[a], 1);
    }
    __syncthreads();
    int* ps = part_src + (size_t)(p * S_SLICES + s) * NP;
    int* pd = part_dst + (size_t)(p * S_SLICES + s) * NP;
    for (int j = tid; j < NP; j += 256) { ps[j] = hs[j]; pd[j] = hd[j]; }
}

// ---------------------------------------------------------------- reduce + prefix + norms
// per node: sum src partials -> out_norm; exclusive prefix over slices of dst
// partials (in place) -> per-slice write bases; total -> deg_in, in_norm.
__global__ void reduce_prefix_norm_kernel(const int* __restrict__ part_src,
                                          int* __restrict__ part_dst,
                                          int* __restrict__ deg_in,
                                          float* __restrict__ out_norm,
                                          float* __restrict__ in_norm) {
    int n = blockIdx.x * blockDim.x + threadIdx.x;
    if (n >= N_NODES) return;
    int p = n / NP, j = n - p * NP;
    size_t base = (size_t)p * S_SLICES * NP + j;
    int so = 0;
    #pragma unroll
    for (int s = 0; s < S_SLICES; s++) so += part_src[base + (size_t)s * NP];
    int run = 0;
    #pragma unroll
    for (int s = 0; s < S_SLICES; s++) {
        int c = part_dst[base + (size_t)s * NP];
        part_dst[base + (size_t)s * NP] = run;
        run += c;
    }
    deg_in[n] = run;
    out_norm[n] = rsqrtf((float)(so < 1 ? 1 : so));
    in_norm[n]  = rsqrtf((float)(run < 1 ? 1 : run));
}

// ---------------------------------------------------------------- 1-block scan
__global__ void scan_kernel(const int* __restrict__ deg, int* __restrict__ row_ptr) {
    __shared__ int sums[1024];
    int t = threadIdx.x;
    int s = 0;
    if (t < 1000) {
        const int4* d4 = (const int4*)(deg + t * 100);
        #pragma unroll
        for (int i = 0; i < 25; i++) { int4 v = d4[i]; s += v.x + v.y + v.z + v.w; }
    }
    sums[t] = s;
    __syncthreads();
    for (int st = 1; st < 1024; st <<= 1) {
        int v = (t >= st) ? sums[t - st] : 0;
        __syncthreads();
        sums[t] += v;
        __syncthreads();
    }
    if (t < 1000) {
        int base = (t == 0) ? 0 : sums[t - 1];
        for (int i = 0; i < 100; i++) { row_ptr[t * 100 + i] = base; base += deg[t * 100 + i]; }
    }
    if (t == 1023) row_ptr[N_NODES] = sums[1023];
}

// ---------------------------------------------------------------- atomic-free CSR fill
// block (p,s): LDS counter gives rank within slice; pos = row_ptr + slice-prefix + rank.
// p = blockIdx&7 -> same-p blocks land on one XCD (round-robin) -> csr span L2-local.
__global__ __launch_bounds__(256) void fill_part_kernel(
    const int* __restrict__ src, const int* __restrict__ dst,
    const int* __restrict__ row_ptr, const int* __restrict__ part_dst,
    int* __restrict__ csr_src) {
    __shared__ int cnt[NP];
    int tid = threadIdx.x;
    int p = blockIdx.x & (P_PARTS - 1), s = blockIdx.x >> 3;
    for (int j = tid; j < NP; j += 256) cnt[j] = 0;
    __syncthreads();
    int lo = p * NP;
    const int* pd = part_dst + (size_t)(p * S_SLICES + s) * NP;
    const int4* s4 = (const int4*)(src + s * ES);
    const int4* d4 = (const int4*)(dst + s * ES);
    for (int i = tid; i < ES / 4; i += 256) {
        int4 sv = s4[i];
        int4 dv = d4[i];
        int a;
        a = dv.x - lo;
        if ((unsigned)a < NP) { int r = atomicAdd(&cnt[a], 1); csr_src[row_ptr[lo + a] + pd[a] + r] = sv.x; }
        a = dv.y - lo;
        if ((unsigned)a < NP) { int r = atomicAdd(&cnt[a], 1); csr_src[row_ptr[lo + a] + pd[a] + r] = sv.y; }
        a = dv.z - lo;
        if ((unsigned)a < NP) { int r = atomicAdd(&cnt[a], 1); csr_src[row_ptr[lo + a] + pd[a] + r] = sv.z; }
        a = dv.w - lo;
        if ((unsigned)a < NP) { int r = atomicAdd(&cnt[a], 1); csr_src[row_ptr[lo + a] + pd[a] + r] = sv.w; }
    }
}

// ---------------------------------------------------------------- weight prep
__global__ void tconv_kernel(const float* __restrict__ in, unsigned short* __restrict__ out,
                             int NN, int KK) {   // in [KK][NN] -> out [NN][KK] bf16
    int idx = blockIdx.x * blockDim.x + threadIdx.x;
    if (idx >= NN * KK) return;
    int n = idx / KK, k = idx % KK;
    out[idx] = f2bf(in[(size_t)k * NN + n]);
}
__global__ void conv_kernel(const float* __restrict__ in, unsigned short* __restrict__ out,
                            int total) {
    int idx = blockIdx.x * blockDim.x + threadIdx.x;
    if (idx < total) out[idx] = f2bf(in[idx]);
}

// ---------------------------------------------------------------- prescale x*out_norm -> bf16
__global__ void prescale_kernel(const float4* __restrict__ in, const float* __restrict__ out_norm,
                                ushort4* __restrict__ out) {
    int idx = blockIdx.x * blockDim.x + threadIdx.x;
    if (idx >= N_NODES * 32) return;
    float sc = out_norm[idx >> 5];
    float4 v = in[idx];
    ushort4 o;
    o.x = f2bf(v.x * sc); o.y = f2bf(v.y * sc); o.z = f2bf(v.z * sc); o.w = f2bf(v.w * sc);
    out[idx] = o;
}

// ---------------------------------------------------------------- aggregation
template<int EPI>
__global__ __launch_bounds__(256) void aggregate_bf(
    const ushort4* __restrict__ x, const int* __restrict__ row_ptr,
    const int* __restrict__ csr_src, const float* __restrict__ in_norm,
    const float* __restrict__ b2, float4* __restrict__ outF,
    ushort4* __restrict__ outB) {
    int wave = threadIdx.x >> 6, lane = threadIdx.x & 63;
    int n = blockIdx.x * 4 + wave;
    if (n >= N_NODES) return;
    int half = lane >> 5, cl = lane & 31;
    int s0 = row_ptr[n], s1 = row_ptr[n + 1];
    float ax = 0, ay = 0, az = 0, aw = 0;
    float bx = 0, by = 0, bz = 0, bw = 0;
    int i = s0 + half;
    for (; i + 6 < s1; i += 8) {
        int sA = csr_src[i],     sB = csr_src[i + 2];
        int sC = csr_src[i + 4], sD = csr_src[i + 6];
        ushort4 va = x[(size_t)sA * 32 + cl];
        ushort4 vb = x[(size_t)sB * 32 + cl];
        ushort4 vc = x[(size_t)sC * 32 + cl];
        ushort4 vd = x[(size_t)sD * 32 + cl];
        ax += bf2f(va.x); ay += bf2f(va.y); az += bf2f(va.z); aw += bf2f(va.w);
        bx += bf2f(vb.x); by += bf2f(vb.y); bz += bf2f(vb.z); bw += bf2f(vb.w);
        ax += bf2f(vc.x); ay += bf2f(vc.y); az += bf2f(vc.z); aw += bf2f(vc.w);
        bx += bf2f(vd.x); by += bf2f(vd.y); bz += bf2f(vd.z); bw += bf2f(vd.w);
    }
    for (; i < s1; i += 2) {
        ushort4 va = x[(size_t)csr_src[i] * 32 + cl];
        ax += bf2f(va.x); ay += bf2f(va.y); az += bf2f(va.z); aw += bf2f(va.w);
    }
    ax += bx; ay += by; az += bz; aw += bw;
    ax += __shfl_xor(ax, 32);
    ay += __shfl_xor(ay, 32);
    az += __shfl_xor(az, 32);
    aw += __shfl_xor(aw, 32);
    float inn = in_norm[n];
    if (EPI == 0) {
        if (half == 0) {
            ushort4 o;
            o.x = f2bf(ax * inn); o.y = f2bf(ay * inn);
            o.z = f2bf(az * inn); o.w = f2bf(aw * inn);
            outB[(size_t)n * 32 + cl] = o;
        }
    } else {
        float4 bv = ((const float4*)b2)[cl];
        float vx = fmaxf(fmaf(ax, inn, bv.x), 0.f);
        float vy = fmaxf(fmaf(ay, inn, bv.y), 0.f);
        float vz = fmaxf(fmaf(az, inn, bv.z), 0.f);
        float vw = fmaxf(fmaf(aw, inn, bv.w), 0.f);
        if (half == 0) {
            outF[(size_t)n * 32 + cl] = make_float4(vx, vy, vz, vw);
        } else {
            ushort4 o;
            o.x = f2bf(vx); o.y = f2bf(vy); o.z = f2bf(vz); o.w = f2bf(vw);
            outB[(size_t)n * 32 + cl] = o;
        }
    }
}

// ---------------------------------------------------------------- bf16 MFMA GEMM
template<int K, int EPI>
__global__ __launch_bounds__(256) void gemm_mfma(
    const unsigned short* __restrict__ A, const unsigned short* __restrict__ Bt,
    const float* __restrict__ aux, void* __restrict__ Cv, int ldc, int M) {
    constexpr int CH = K / 8;
    __shared__ short blds[128 * K];
    int tid = threadIdx.x;
    int bn = blockIdx.x * 128;
    int bm = blockIdx.y * 128;
    {
        const short8* g = (const short8*)Bt;
        short8* l = (short8*)blds;
        for (int id = tid; id < 128 * CH; id += 256) {
            int col = id / CH, kc = id % CH;
            l[col * CH + (kc ^ (col & (CH - 1)))] = g[(size_t)(bn + col) * CH + kc];
        }
    }
    __syncthreads();
    int wm = tid >> 6, lane = tid & 63;
    int lr = lane & 15, kq = lane >> 4;
    int r0 = bm + wm * 32 + lr;
    int r1 = r0 + 16;
    const short8* A8 = (const short8*)A;
    size_t a0row = (size_t)(r0 < M ? r0 : 0) * CH;
    size_t a1row = (size_t)(r1 < M ? r1 : 0) * CH;
    const short8* l8 = (const short8*)blds;

    f32x4 acc[2][8];
    #pragma unroll
    for (int m = 0; m < 2; m++)
        #pragma unroll
        for (int j = 0; j < 8; j++) acc[m][j] = (f32x4)0.f;

    short8 a0 = A8[a0row + kq];
    short8 a1 = A8[a1row + kq];
    for (int kc2 = 0; kc2 < K / 32; kc2++) {
        int kc = kc2 * 4 + kq;
        short8 n0, n1;
        if (kc2 + 1 < K / 32) {
            n0 = A8[a0row + kc + 4];
            n1 = A8[a1row + kc + 4];
        }
        #pragma unroll
        for (int nj = 0; nj < 8; nj++) {
            int col = nj * 16 + lr;
            short8 b = l8[col * CH + (kc ^ (col & (CH - 1)))];
            acc[0][nj] = __builtin_amdgcn_mfma_f32_16x16x32_bf16(a0, b, acc[0][nj], 0, 0, 0);
            acc[1][nj] = __builtin_amdgcn_mfma_f32_16x16x32_bf16(a1, b, acc[1][nj], 0, 0, 0);
        }
        a0 = n0; a1 = n1;
    }

    #pragma unroll
    for (int mi = 0; mi < 2; mi++) {
        #pragma unroll
        for (int i = 0; i < 4; i++) {
            int gr = bm + wm * 32 + mi * 16 + kq * 4 + i;
            if (gr >= M) continue;
            float sc = (EPI == 2) ? aux[gr] : 0.f;
            #pragma unroll
            for (int nj = 0; nj < 8; nj++) {
                int col = bn + nj * 16 + lr;
                float v = acc[mi][nj][i];
                if (EPI == 0)
                    ((float*)Cv)[(size_t)gr * ldc + col] = v;
                else if (EPI == 1)
                    ((unsigned short*)Cv)[(size_t)gr * ldc + col] = f2bf(fmaxf(v + aux[col], 0.f));
                else
                    ((unsigned short*)Cv)[(size_t)gr * ldc + col] = f2bf(v * sc);
            }
        }
    }
}

// ================================================================ launch
extern "C" void kernel_launch(void* const* d_in, const int* in_sizes, int n_in,
                              void* d_out, int out_size, void* d_ws, size_t ws_size,
                              hipStream_t stream) {
    const float* in_feat = (const float*)d_in[0];
    const int*   src     = (const int*)d_in[1];
    const int*   dst     = (const int*)d_in[2];
    const float* W1      = (const float*)d_in[3];   // [128][256]
    const float* b1      = (const float*)d_in[4];
    const float* W2      = (const float*)d_in[5];   // [256][128]
    const float* b2      = (const float*)d_in[6];
    const float* fc1_w   = (const float*)d_in[7];
    const float* fc2_w   = (const float*)d_in[8];

    float* out = (float*)d_out;
    float* h_out = out;                              // [100000][128] f32 (final)
    float* feat1 = out + (size_t)12800000;
    float* feat2 = out + (size_t)25600000;
    // scratch aliases in d_out (lifetimes verified against writers):
    unsigned short* xs_bf   = (unsigned short*)out;              // dies before agg2 writes h
    unsigned short* agg1_bf = (unsigned short*)(out + 6400000);  // dies before agg2 writes h
    unsigned short* h1_bf   = (unsigned short*)(out + 12800000); // dies before feat1 written
    unsigned short* x2_bf   = (unsigned short*)(out + 25600000); // dies before feat2 written

    // workspace
    int* part_dst = (int*)d_ws;                      // [8][32][12500] = 3.2M ints
    int* part_src = part_dst + P_PARTS * S_SLICES * NP;   // 3.2M ints
    int* csr_src  = part_src;                        // alias: part_src dead after reduce
    int* deg_in   = part_src + P_PARTS * S_SLICES * NP;   // 100000
    int* row_ptr  = deg_in + 100000;                 // 100004
    float* out_norm = (float*)(row_ptr + 100004);
    float* in_norm  = out_norm + 100000;
    unsigned short* Wt1  = (unsigned short*)(in_norm + 100000);  // [256][128]
    unsigned short* Wt2  = Wt1 + 32768;                          // [128][256]
    unsigned short* fc1b = Wt2 + 32768;
    unsigned short* fc2b = fc1b + 16384;
    unsigned short* h_bf = fc2b + 16384;                         // [100000][128]

    // CSR build — no global atomics
    hist_part_kernel<<<P_PARTS * S_SLICES, 256, 0, stream>>>(src, dst, part_src, part_dst);
    reduce_prefix_norm_kernel<<<(N_NODES + 255) / 256, 256, 0, stream>>>(
        part_src, part_dst, deg_in, out_norm, in_norm);
    scan_kernel<<<1, 1024, 0, stream>>>(deg_in, row_ptr);
    fill_part_kernel<<<P_PARTS * S_SLICES, 256, 0, stream>>>(src, dst, row_ptr, part_dst, csr_src);

    tconv_kernel<<<128, 256, 0, stream>>>(W1, Wt1, 256, 128);
    tconv_kernel<<<128, 256, 0, stream>>>(W2, Wt2, 128, 256);
    conv_kernel<<<64, 256, 0, stream>>>(fc1_w, fc1b, 16384);
    conv_kernel<<<64, 256, 0, stream>>>(fc2_w, fc2b, 16384);

    prescale_kernel<<<12500, 256, 0, stream>>>((const float4*)in_feat, out_norm, (ushort4*)xs_bf);

    aggregate_bf<0><<<25000, 256, 0, stream>>>((const ushort4*)xs_bf, row_ptr, csr_src,
                                               in_norm, nullptr, nullptr, (ushort4*)agg1_bf);

    gemm_mfma<128, 1><<<dim3(2, 782), 256, 0, stream>>>(agg1_bf, Wt1, b1, h1_bf, 256, N_NODES);
    gemm_mfma<256, 2><<<dim3(1, 782), 256, 0, stream>>>(h1_bf, Wt2, out_norm, x2_bf, 128, N_NODES);

    aggregate_bf<1><<<25000, 256, 0, stream>>>((const ushort4*)x2_bf, row_ptr, csr_src,
                                               in_norm, b2, (float4*)h_out, (ushort4*)h_bf);

    gemm_mfma<128, 0><<<dim3(1, 782), 256, 0, stream>>>(h_bf, fc1b, nullptr, feat1, 128, N_NODES);
    gemm_mfma<128, 0><<<dim3(1, 782), 256, 0, stream>>>(h_bf, fc2b, nullptr, feat2, 128, N_NODES);
}

// Round 6
// 400.173 us; speedup vs baseline: 1.3676x; 1.0125x over previous
//
#include <hip/hip_runtime.h>

#define N_NODES 100000
#define N_EDGES 1600000
#define P_PARTS 8
#define S_SLICES 32
#define NP 12500     // nodes per partition
#define ES 50000     // edges per slice
#define FEAT2_OFF 12800000

typedef __attribute__((ext_vector_type(8))) short short8;
typedef __attribute__((ext_vector_type(8))) unsigned short ushort8v;
typedef __attribute__((ext_vector_type(4))) float f32x4;

__device__ inline float bf2f(unsigned short h) {
    union { unsigned int u; float f; } v; v.u = ((unsigned int)h) << 16; return v.f;
}
__device__ inline unsigned short f2bf(float f) {
    union { unsigned int u; float f; } v; v.f = f;
    unsigned int u = v.u;
    return (unsigned short)((u + 0x7fffu + ((u >> 16) & 1u)) >> 16);
}

// ---------------------------------------------------------------- partitioned LDS histograms
__global__ __launch_bounds__(256) void hist_part_kernel(
    const int* __restrict__ src, const int* __restrict__ dst,
    int* __restrict__ part_src, int* __restrict__ part_dst) {
    __shared__ int hs[NP];
    __shared__ int hd[NP];
    int tid = threadIdx.x;
    int p = blockIdx.x & (P_PARTS - 1), s = blockIdx.x >> 3;
    for (int j = tid; j < NP; j += 256) { hs[j] = 0; hd[j] = 0; }
    __syncthreads();
    int lo = p * NP;
    const int4* s4 = (const int4*)(src + s * ES);
    const int4* d4 = (const int4*)(dst + s * ES);
    for (int i = tid; i < ES / 4; i += 256) {
        int4 sv = s4[i];
        int4 dv = d4[i];
        int a;
        a = sv.x - lo; if ((unsigned)a < NP) atomicAdd(&hs[a], 1);
        a = sv.y - lo; if ((unsigned)a < NP) atomicAdd(&hs[a], 1);
        a = sv.z - lo; if ((unsigned)a < NP) atomicAdd(&hs[a], 1);
        a = sv.w - lo; if ((unsigned)a < NP) atomicAdd(&hs[a], 1);
        a = dv.x - lo; if ((unsigned)a < NP) atomicAdd(&hd[a], 1);
        a = dv.y - lo; if ((unsigned)a < NP) atomicAdd(&hd[a], 1);
        a = dv.z - lo; if ((unsigned)a < NP) atomicAdd(&hd[a], 1);
        a = dv.w - lo; if ((unsigned)a < NP) atomicAdd(&hd[a], 1);
    }
    __syncthreads();
    int* ps = part_src + (size_t)(p * S_SLICES + s) * NP;
    int* pd = part_dst + (size_t)(p * S_SLICES + s) * NP;
    for (int j = tid; j < NP; j += 256) { ps[j] = hs[j]; pd[j] = hd[j]; }
}

// ---------------------------------------------------------------- reduce + prefix + norms
__global__ void reduce_prefix_norm_kernel(const int* __restrict__ part_src,
                                          int* __restrict__ part_dst,
                                          int* __restrict__ deg_in,
                                          float* __restrict__ out_norm,
                                          float* __restrict__ in_norm) {
    int n = blockIdx.x * blockDim.x + threadIdx.x;
    if (n >= N_NODES) return;
    int p = n / NP, j = n - p * NP;
    size_t base = (size_t)p * S_SLICES * NP + j;
    int so = 0;
    #pragma unroll
    for (int s = 0; s < S_SLICES; s++) so += part_src[base + (size_t)s * NP];
    int run = 0;
    #pragma unroll
    for (int s = 0; s < S_SLICES; s++) {
        int c = part_dst[base + (size_t)s * NP];
        part_dst[base + (size_t)s * NP] = run;
        run += c;
    }
    deg_in[n] = run;
    out_norm[n] = rsqrtf((float)(so < 1 ? 1 : so));
    in_norm[n]  = rsqrtf((float)(run < 1 ? 1 : run));
}

// ---------------------------------------------------------------- 1-block scan
__global__ void scan_kernel(const int* __restrict__ deg, int* __restrict__ row_ptr) {
    __shared__ int sums[1024];
    int t = threadIdx.x;
    int s = 0;
    if (t < 1000) {
        const int4* d4 = (const int4*)(deg + t * 100);
        #pragma unroll
        for (int i = 0; i < 25; i++) { int4 v = d4[i]; s += v.x + v.y + v.z + v.w; }
    }
    sums[t] = s;
    __syncthreads();
    for (int st = 1; st < 1024; st <<= 1) {
        int v = (t >= st) ? sums[t - st] : 0;
        __syncthreads();
        sums[t] += v;
        __syncthreads();
    }
    if (t < 1000) {
        int base = (t == 0) ? 0 : sums[t - 1];
        for (int i = 0; i < 100; i++) { row_ptr[t * 100 + i] = base; base += deg[t * 100 + i]; }
    }
    if (t == 1023) row_ptr[N_NODES] = sums[1023];
}

// ---------------------------------------------------------------- atomic-free CSR fill
__global__ __launch_bounds__(256) void fill_part_kernel(
    const int* __restrict__ src, const int* __restrict__ dst,
    const int* __restrict__ row_ptr, const int* __restrict__ part_dst,
    int* __restrict__ csr_src) {
    __shared__ int cnt[NP];
    int tid = threadIdx.x;
    int p = blockIdx.x & (P_PARTS - 1), s = blockIdx.x >> 3;
    for (int j = tid; j < NP; j += 256) cnt[j] = 0;
    __syncthreads();
    int lo = p * NP;
    const int* pd = part_dst + (size_t)(p * S_SLICES + s) * NP;
    const int4* s4 = (const int4*)(src + s * ES);
    const int4* d4 = (const int4*)(dst + s * ES);
    for (int i = tid; i < ES / 4; i += 256) {
        int4 sv = s4[i];
        int4 dv = d4[i];
        int a;
        a = dv.x - lo;
        if ((unsigned)a < NP) { int r = atomicAdd(&cnt[a], 1); csr_src[row_ptr[lo + a] + pd[a] + r] = sv.x; }
        a = dv.y - lo;
        if ((unsigned)a < NP) { int r = atomicAdd(&cnt[a], 1); csr_src[row_ptr[lo + a] + pd[a] + r] = sv.y; }
        a = dv.z - lo;
        if ((unsigned)a < NP) { int r = atomicAdd(&cnt[a], 1); csr_src[row_ptr[lo + a] + pd[a] + r] = sv.z; }
        a = dv.w - lo;
        if ((unsigned)a < NP) { int r = atomicAdd(&cnt[a], 1); csr_src[row_ptr[lo + a] + pd[a] + r] = sv.w; }
    }
}

// ---------------------------------------------------------------- merged weight prep
// [0,32768): Wt1[n][k]=W1[k][n] (n<256,k<128); [32768,65536): Wt2[n][k]=W2[k][n] (n<128,k<256)
// [65536,98304): fcb = [fc1b;fc2b] straight convert
__global__ void prep_weights_kernel(const float* __restrict__ W1, const float* __restrict__ W2,
                                    const float* __restrict__ fc1, const float* __restrict__ fc2,
                                    unsigned short* __restrict__ Wt1, unsigned short* __restrict__ Wt2,
                                    unsigned short* __restrict__ fcb) {
    int idx = blockIdx.x * blockDim.x + threadIdx.x;
    if (idx < 32768) {
        int n = idx >> 7, k = idx & 127;
        Wt1[idx] = f2bf(W1[k * 256 + n]);
    } else if (idx < 65536) {
        int t = idx - 32768;
        int n = t >> 8, k = t & 255;
        Wt2[t] = f2bf(W2[k * 128 + n]);
    } else if (idx < 98304) {
        int t = idx - 65536;
        fcb[t] = f2bf(t < 16384 ? fc1[t] : fc2[t - 16384]);
    }
}

// ---------------------------------------------------------------- prescale x*out_norm -> bf16
__global__ void prescale_kernel(const float4* __restrict__ in, const float* __restrict__ out_norm,
                                ushort4* __restrict__ out) {
    int idx = blockIdx.x * blockDim.x + threadIdx.x;
    if (idx >= N_NODES * 32) return;
    float sc = out_norm[idx >> 5];
    float4 v = in[idx];
    ushort4 o;
    o.x = f2bf(v.x * sc); o.y = f2bf(v.y * sc); o.z = f2bf(v.z * sc); o.w = f2bf(v.w * sc);
    out[idx] = o;
}

// ---------------------------------------------------------------- aggregation v3
// one wave per dst node; quarter-wave (16 lanes x ushort8 = 256B) covers one bf16 row;
// 4 quarters x 4-deep unroll -> 16 independent row gathers in flight per wave.
// EPI 0: out_bf = bf16(sum * in_norm)          (agg1)
// EPI 1: v = relu(sum*in_norm + b2); f32 -> outF, bf16 -> outB   (agg2)
template<int EPI>
__global__ __launch_bounds__(256) void aggregate_bf(
    const unsigned short* __restrict__ x, const int* __restrict__ row_ptr,
    const int* __restrict__ csr_src, const float* __restrict__ in_norm,
    const float* __restrict__ b2, float4* __restrict__ outF,
    unsigned short* __restrict__ outB) {
    int wave = threadIdx.x >> 6, lane = threadIdx.x & 63;
    int n = blockIdx.x * 4 + wave;
    if (n >= N_NODES) return;
    int q = lane >> 4, ql = lane & 15;
    int s0 = row_ptr[n], s1 = row_ptr[n + 1];
    const ushort8v* xf = (const ushort8v*)x;       // 16 chunks per 128-feat row
    float a0[8], a1[8];
    #pragma unroll
    for (int j = 0; j < 8; j++) { a0[j] = 0.f; a1[j] = 0.f; }
    int i = s0 + q;
    for (; i + 12 < s1; i += 16) {
        int sA = csr_src[i],     sB = csr_src[i + 4];
        int sC = csr_src[i + 8], sD = csr_src[i + 12];
        ushort8v va = xf[(size_t)sA * 16 + ql];
        ushort8v vb = xf[(size_t)sB * 16 + ql];
        ushort8v vc = xf[(size_t)sC * 16 + ql];
        ushort8v vd = xf[(size_t)sD * 16 + ql];
        #pragma unroll
        for (int j = 0; j < 8; j++) a0[j] += bf2f(va[j]) + bf2f(vc[j]);
        #pragma unroll
        for (int j = 0; j < 8; j++) a1[j] += bf2f(vb[j]) + bf2f(vd[j]);
    }
    for (; i < s1; i += 4) {
        ushort8v va = xf[(size_t)csr_src[i] * 16 + ql];
        #pragma unroll
        for (int j = 0; j < 8; j++) a0[j] += bf2f(va[j]);
    }
    #pragma unroll
    for (int j = 0; j < 8; j++) {
        float v = a0[j] + a1[j];
        v += __shfl_xor(v, 16);
        v += __shfl_xor(v, 32);
        a0[j] = v;
    }
    float inn = in_norm[n];
    if (EPI == 0) {
        if (q == 0) {
            ushort8v o;
            #pragma unroll
            for (int j = 0; j < 8; j++) o[j] = f2bf(a0[j] * inn);
            ((ushort8v*)outB)[(size_t)n * 16 + ql] = o;
        }
    } else {
        const float4* b4 = (const float4*)b2;
        float4 blo = b4[ql * 2], bhi = b4[ql * 2 + 1];
        float v[8];
        v[0] = fmaxf(fmaf(a0[0], inn, blo.x), 0.f);
        v[1] = fmaxf(fmaf(a0[1], inn, blo.y), 0.f);
        v[2] = fmaxf(fmaf(a0[2], inn, blo.z), 0.f);
        v[3] = fmaxf(fmaf(a0[3], inn, blo.w), 0.f);
        v[4] = fmaxf(fmaf(a0[4], inn, bhi.x), 0.f);
        v[5] = fmaxf(fmaf(a0[5], inn, bhi.y), 0.f);
        v[6] = fmaxf(fmaf(a0[6], inn, bhi.z), 0.f);
        v[7] = fmaxf(fmaf(a0[7], inn, bhi.w), 0.f);
        if (q == 0) {
            ushort8v o;
            #pragma unroll
            for (int j = 0; j < 8; j++) o[j] = f2bf(v[j]);
            ((ushort8v*)outB)[(size_t)n * 16 + ql] = o;
        } else if (q == 1) {
            outF[(size_t)n * 32 + ql * 2] = make_float4(v[0], v[1], v[2], v[3]);
        } else if (q == 2) {
            outF[(size_t)n * 32 + ql * 2 + 1] = make_float4(v[4], v[5], v[6], v[7]);
        }
    }
}

// ---------------------------------------------------------------- bf16 MFMA GEMM
// C[M x NF*16] = A[M][K](bf16) @ Bt[N][K](bf16)^T; full-K, full-N in one block.
// EPI: 1 = bf16(relu(v+aux[col])); 2 = bf16(v*aux[row]); 3 = f32 split-store feat1/feat2
template<int K, int NF, int EPI>
__global__ __launch_bounds__(256) void gemm_mfma(
    const unsigned short* __restrict__ A, const unsigned short* __restrict__ Bt,
    const float* __restrict__ aux, void* __restrict__ Cv, int ldc, int M) {
    constexpr int CH = K / 8;
    __shared__ short blds[NF * 16 * K];
    int tid = threadIdx.x;
    int bn = blockIdx.x * (NF * 16);
    int bm = blockIdx.y * 128;
    {
        const short8* g = (const short8*)Bt;
        short8* l = (short8*)blds;
        for (int id = tid; id < NF * 16 * CH; id += 256) {
            int col = id / CH, kc = id % CH;
            l[col * CH + (kc ^ (col & (CH - 1)))] = g[(size_t)(bn + col) * CH + kc];
        }
    }
    __syncthreads();
    int wm = tid >> 6, lane = tid & 63;
    int lr = lane & 15, kq = lane >> 4;
    int r0 = bm + wm * 32 + lr;
    int r1 = r0 + 16;
    const short8* A8 = (const short8*)A;
    size_t a0row = (size_t)(r0 < M ? r0 : 0) * CH;
    size_t a1row = (size_t)(r1 < M ? r1 : 0) * CH;
    const short8* l8 = (const short8*)blds;

    f32x4 acc[2][NF];
    #pragma unroll
    for (int m = 0; m < 2; m++)
        #pragma unroll
        for (int j = 0; j < NF; j++) acc[m][j] = (f32x4)0.f;

    short8 a0 = A8[a0row + kq];
    short8 a1 = A8[a1row + kq];
    for (int kc2 = 0; kc2 < K / 32; kc2++) {
        int kc = kc2 * 4 + kq;
        short8 n0, n1;
        if (kc2 + 1 < K / 32) {
            n0 = A8[a0row + kc + 4];
            n1 = A8[a1row + kc + 4];
        }
        #pragma unroll
        for (int nj = 0; nj < NF; nj++) {
            int col = nj * 16 + lr;
            short8 b = l8[col * CH + (kc ^ (col & (CH - 1)))];
            acc[0][nj] = __builtin_amdgcn_mfma_f32_16x16x32_bf16(a0, b, acc[0][nj], 0, 0, 0);
            acc[1][nj] = __builtin_amdgcn_mfma_f32_16x16x32_bf16(a1, b, acc[1][nj], 0, 0, 0);
        }
        a0 = n0; a1 = n1;
    }

    #pragma unroll
    for (int mi = 0; mi < 2; mi++) {
        #pragma unroll
        for (int i = 0; i < 4; i++) {
            int gr = bm + wm * 32 + mi * 16 + kq * 4 + i;
            if (gr >= M) continue;
            float sc = (EPI == 2) ? aux[gr] : 0.f;
            #pragma unroll
            for (int nj = 0; nj < NF; nj++) {
                int col = bn + nj * 16 + lr;
                float v = acc[mi][nj][i];
                if (EPI == 1)
                    ((unsigned short*)Cv)[(size_t)gr * ldc + col] = f2bf(fmaxf(v + aux[col], 0.f));
                else if (EPI == 2)
                    ((unsigned short*)Cv)[(size_t)gr * ldc + col] = f2bf(v * sc);
                else {
                    float* dstp = (float*)Cv + (size_t)(col >= 128 ? FEAT2_OFF : 0)
                                  + (size_t)gr * 128 + (col & 127);
                    *dstp = v;
                }
            }
        }
    }
}

// ================================================================ launch
extern "C" void kernel_launch(void* const* d_in, const int* in_sizes, int n_in,
                              void* d_out, int out_size, void* d_ws, size_t ws_size,
                              hipStream_t stream) {
    const float* in_feat = (const float*)d_in[0];
    const int*   src     = (const int*)d_in[1];
    const int*   dst     = (const int*)d_in[2];
    const float* W1      = (const float*)d_in[3];   // [128][256]
    const float* b1      = (const float*)d_in[4];
    const float* W2      = (const float*)d_in[5];   // [256][128]
    const float* b2      = (const float*)d_in[6];
    const float* fc1_w   = (const float*)d_in[7];
    const float* fc2_w   = (const float*)d_in[8];

    float* out = (float*)d_out;
    float* h_out = out;                              // [100000][128] f32 (final)
    float* feat1 = out + (size_t)12800000;
    // scratch aliases in d_out (lifetimes verified against writers):
    unsigned short* xs_bf   = (unsigned short*)out;              // dies before agg2 writes h
    unsigned short* agg1_bf = (unsigned short*)(out + 6400000);  // dies before agg2 writes h
    unsigned short* h1_bf   = (unsigned short*)(out + 12800000); // dies before feat1 written
    unsigned short* x2_bf   = (unsigned short*)(out + 25600000); // dies before feat2 written

    // workspace
    int* part_dst = (int*)d_ws;                           // [8][32][12500]
    int* part_src = part_dst + P_PARTS * S_SLICES * NP;   // [8][32][12500]
    int* csr_src  = part_src;                             // alias: part_src dead after reduce
    int* deg_in   = part_src + P_PARTS * S_SLICES * NP;   // 100000
    int* row_ptr  = deg_in + 100000;                      // 100004
    float* out_norm = (float*)(row_ptr + 100004);
    float* in_norm  = out_norm + 100000;
    unsigned short* Wt1 = (unsigned short*)(in_norm + 100000);  // [256][128]
    unsigned short* Wt2 = Wt1 + 32768;                          // [128][256]
    unsigned short* fcb = Wt2 + 32768;                          // [256][128] = [fc1b;fc2b]
    unsigned short* h_bf = fcb + 32768;                         // [100000][128]

    // CSR build — no global atomics
    hist_part_kernel<<<P_PARTS * S_SLICES, 256, 0, stream>>>(src, dst, part_src, part_dst);
    reduce_prefix_norm_kernel<<<(N_NODES + 255) / 256, 256, 0, stream>>>(
        part_src, part_dst, deg_in, out_norm, in_norm);
    scan_kernel<<<1, 1024, 0, stream>>>(deg_in, row_ptr);
    fill_part_kernel<<<P_PARTS * S_SLICES, 256, 0, stream>>>(src, dst, row_ptr, part_dst, csr_src);

    prep_weights_kernel<<<384, 256, 0, stream>>>(W1, W2, fc1_w, fc2_w, Wt1, Wt2, fcb);

    prescale_kernel<<<12500, 256, 0, stream>>>((const float4*)in_feat, out_norm, (ushort4*)xs_bf);

    aggregate_bf<0><<<25000, 256, 0, stream>>>(xs_bf, row_ptr, csr_src,
                                               in_norm, nullptr, nullptr, agg1_bf);

    gemm_mfma<128, 16, 1><<<dim3(1, 782), 256, 0, stream>>>(agg1_bf, Wt1, b1, h1_bf, 256, N_NODES);
    gemm_mfma<256, 8, 2><<<dim3(1, 782), 256, 0, stream>>>(h1_bf, Wt2, out_norm, x2_bf, 128, N_NODES);

    aggregate_bf<1><<<25000, 256, 0, stream>>>(x2_bf, row_ptr, csr_src,
                                               in_norm, b2, (float4*)h_out, h_bf);

    gemm_mfma<128, 16, 3><<<dim3(1, 782), 256, 0, stream>>>(h_bf, fcb, nullptr, feat1, 128, N_NODES);
}